// Round 3
// baseline (732.350 us; speedup 1.0000x reference)
//
#include <hip/hip_runtime.h>
#include <hip/hip_bf16.h>
#include <math.h>

// RelationAwareTreeLSTMCell on gfx950 — fused single kernel, dtype-probing variants.
// B=4096 N=32 H=256 DIN=256 R=3. Block = 16 batches, 4 chunks of 4.
// Four template variants <F32 inputs?, MASK8 bool-as-byte?> are all launched; each
// probes the input encoding (uniform, deterministic) and exits unless it matches.

#define B_   4096
#define N_   32
#define H_   256
#define DIN_ 256
#define R_   3
#define MB   16     // batches per block
#define NBC  4      // batches per chunk
#define DECAY 0.7f

typedef __bf16 bf16;
typedef bf16  bf16x8 __attribute__((ext_vector_type(8)));
typedef float f32x4  __attribute__((ext_vector_type(4)));

__device__ __forceinline__ float sigmoidf_(float x) { return 1.0f / (1.0f + __expf(-x)); }

template<bool F32>
__device__ __forceinline__ float ld1(const void* p, size_t i) {
    if constexpr (F32) return ((const float*)p)[i];
    else               return (float)((const bf16*)p)[i];
}

template<bool F32>
__device__ __forceinline__ bf16x8 ld8(const void* p, size_t i) {
    if constexpr (F32) {
        const float* f = (const float*)p + i;
        bf16x8 r;
        #pragma unroll
        for (int j = 0; j < 8; ++j) r[j] = (bf16)f[j];
        return r;
    } else {
        return *(const bf16x8*)((const bf16*)p + i);
    }
}

template<bool F32, bool M8>
__global__ __launch_bounds__(512, 2) void fused_treelstm(
    const void* __restrict__ ivec,
    const void* __restrict__ child_h, const void* __restrict__ child_c,
    const int*  __restrict__ rel_ids, const void* __restrict__ vmaskp,
    const void* __restrict__ rel_emb,
    const void* __restrict__ W_i, const void* __restrict__ b_i,
    const void* __restrict__ W_f, const void* __restrict__ b_f,
    const void* __restrict__ W_o, const void* __restrict__ b_o,
    const void* __restrict__ W_u, const void* __restrict__ b_u,
    const void* __restrict__ w_att, const void* __restrict__ b_att,
    void* __restrict__ outp)
{
    __shared__ __align__(16) bf16 chs[NBC][N_][264];   // 67584 B
    __shared__ __align__(16) bf16 hsumL[MB][264];      //  8448 B
    __shared__ float csL[MB][H_];                      // 16384 B
    __shared__ float watt[H_];                         //  1024 B
    __shared__ float bfl[R_][H_];                      //  3072 B
    __shared__ float dall[MB][N_];                     //  2048 B
    __shared__ int   rids[MB][N_];                     //  2048 B
    __shared__ float scoreT[NBC][N_];
    __shared__ float attnd[NBC][N_];
    __shared__ float rdotL[4];
    __shared__ int   probe_f32, probe_m8;

    const int tid  = threadIdx.x;
    const int wave = tid >> 6;
    const int lane = tid & 63;
    const int t    = lane & 15;
    const int q    = lane >> 4;
    const int b0   = blockIdx.x * MB;

    // ---- dtype probe (uniform across grid; decides which variant proceeds) ----
    if (wave == 0) {
        // bf16 plausibility of child_h's first 1024 half-words.
        // bf16 N(0,1): exponent in [110,140] for ~all. fp32-as-bf16: only ~55%.
        const unsigned short* us = (const unsigned short*)child_h;
        int cnt = 0;
        #pragma unroll
        for (int j = 0; j < 16; ++j) {
            int e = (us[lane * 16 + j] >> 7) & 0xFF;
            cnt += (e >= 110 && e <= 140) ? 1 : 0;
        }
        #pragma unroll
        for (int off = 32; off >= 1; off >>= 1) cnt += __shfl_xor(cnt, off);
        if (lane == 0) probe_f32 = (cnt < 900) ? 1 : 0;
    }
    if (wave == 1) {
        // int32 bools have bytes 1..3 of each word == 0; byte bools are random 0/1.
        const unsigned char* vb = (const unsigned char*)vmaskp;
        int bad = 0;
        #pragma unroll
        for (int j = 1; j < 4; ++j) bad |= vb[lane * 4 + j];
        unsigned long long any = __ballot(bad != 0);
        if (lane == 0) probe_m8 = (any != 0ull) ? 1 : 0;
    }
    __syncthreads();
    if (((probe_f32 != 0) != F32) || ((probe_m8 != 0) != M8)) return;

    // ---- upfront small tables ----
    if (tid < H_) watt[tid] = ld1<F32>(w_att, tid);
    {
        int idx = b0 * N_ + tid;           // MB*N_ == 512 == blockDim
        rids[tid >> 5][tid & 31] = rel_ids[idx];
        bool vm = M8 ? (((const unsigned char*)vmaskp)[idx] != 0)
                     : (((const int*)vmaskp)[idx] != 0);
        dall[tid >> 5][tid & 31] = vm ? DECAY : 1.0f;
    }
    for (int i = tid; i < R_ * H_; i += 512) ((float*)bfl)[i] = ld1<F32>(b_f, i);
    if (tid == 0) rdotL[3] = ld1<F32>(b_att, 0);
    __syncthreads();

    // rdot[r] = dot(rel_emb[r], w_att)  (published by loop-top barrier at ck==0)
    if (wave < R_) {
        int r = wave;
        float p = 0.f;
        #pragma unroll
        for (int j = 0; j < 4; ++j) {
            int h = lane * 4 + j;
            p += ld1<F32>(rel_emb, r * H_ + h) * watt[h];
        }
        #pragma unroll
        for (int off = 32; off >= 1; off >>= 1) p += __shfl_xor(p, off);
        if (lane == 0) rdotL[r] = p;
    }

    // ================= chunk loop: 4 batches each =================
    for (int ck = 0; ck < 4; ++ck) {
        __syncthreads();

        // ---- stage child_h chunk into LDS ----
        {
            size_t base = (size_t)(b0 + ck * NBC) * (N_ * H_);
            #pragma unroll
            for (int it = 0; it < 8; ++it) {
                int e  = it * 512 + tid;
                int ge = e << 3;
                int bi = ge >> 13, n = (ge >> 8) & 31, h = ge & 255;
                *(bf16x8*)(&chs[bi][n][h]) = ld8<F32>(child_h, base + ge);
            }
        }
        __syncthreads();

        // ---- raw attention dots t_n = <ch_n, w_att> ----
        {
            int bi = tid >> 7, idx = tid & 127;
            int n = idx >> 2, part = idx & 3;
            const bf16* row = chs[bi][n];
            float p = 0.f;
            #pragma unroll 16
            for (int h = part * 64; h < part * 64 + 64; ++h) p += (float)row[h] * watt[h];
            p += __shfl_xor(p, 1);
            p += __shfl_xor(p, 2);
            if (part == 0) scoreT[bi][n] = p;
        }
        __syncthreads();

        // ---- softmax over n ----
        if (tid < NBC * N_) {
            int bi = tid >> 5, n = tid & 31;
            int bl = ck * NBC + bi;
            float d = dall[bl][n];
            float s = d * scoreT[bi][n] + rdotL[rids[bl][n]] + rdotL[3];
            float m = s;
            #pragma unroll
            for (int off = 16; off >= 1; off >>= 1) m = fmaxf(m, __shfl_xor(m, off));
            float e = __expf(s - m);
            float sum = e;
            #pragma unroll
            for (int off = 16; off >= 1; off >>= 1) sum += __shfl_xor(sum, off);
            attnd[bi][n] = (e / sum) * d;   // attn * decay
        }
        __syncthreads();

        // ---- h_sum -> LDS (bf16) ----
        {
            int bi = tid >> 7, g = tid & 127;
            int bl = ck * NBC + bi;
            float s0 = 0.f, s1 = 0.f;
            #pragma unroll 8
            for (int n = 0; n < N_; ++n) {
                float w = attnd[bi][n];
                s0 += w * (float)chs[bi][n][g];
                s1 += w * (float)chs[bi][n][g + 128];
            }
            hsumL[bl][g]       = (bf16)s0;
            hsumL[bl][g + 128] = (bf16)s1;
        }

        // ---- rid-masked MFMA GEMM: Q[g,n] (M=256, N=64, K=3x256) ----
        f32x4 acc[2][8];
        #pragma unroll
        for (int i = 0; i < 2; ++i)
            #pragma unroll
            for (int j = 0; j < 8; ++j)
                #pragma unroll
                for (int c = 0; c < 4; ++c) acc[i][j][c] = 0.0f;

        bf16x8 bzero;
        #pragma unroll
        for (int i = 0; i < 8; ++i) bzero[i] = (bf16)0.0f;

        int myrid[8];
        #pragma unroll
        for (int nt = 0; nt < 8; ++nt)
            myrid[nt] = rids[ck * NBC + (nt >> 1)][((nt & 1) << 4) + t];

        #pragma unroll
        for (int r = 0; r < R_; ++r) {
            #pragma unroll
            for (int kc = 0; kc < 8; ++kc) {
                const int k = kc * 32 + q * 8;
                bf16x8 afrag[2];
                #pragma unroll
                for (int m2 = 0; m2 < 2; ++m2) {
                    int g = (wave * 2 + m2) * 16 + t;
                    afrag[m2] = ld8<F32>(W_f, (size_t)(r * H_ + g) * H_ + k);
                }
                #pragma unroll
                for (int nt = 0; nt < 8; ++nt) {
                    int bi = nt >> 1, n = ((nt & 1) << 4) + t;
                    bf16x8 v = *(const bf16x8*)(&chs[bi][n][k]);
                    v = (myrid[nt] == r) ? v : bzero;
                    acc[0][nt] = __builtin_amdgcn_mfma_f32_16x16x32_bf16(afrag[0], v, acc[0][nt], 0, 0, 0);
                    acc[1][nt] = __builtin_amdgcn_mfma_f32_16x16x32_bf16(afrag[1], v, acc[1][nt], 0, 0, 0);
                }
            }
        }
        __syncthreads();

        // ---- stage child_c chunk (overwrite chs) ----
        {
            size_t base = (size_t)(b0 + ck * NBC) * (N_ * H_);
            #pragma unroll
            for (int it = 0; it < 8; ++it) {
                int e  = it * 512 + tid;
                int ge = e << 3;
                int bi = ge >> 13, n = (ge >> 8) & 31, h = ge & 255;
                *(bf16x8*)(&chs[bi][n][h]) = ld8<F32>(child_c, base + ge);
            }
        }
        __syncthreads();

        // ---- cs[bl][g] = sum_n cc*d*(d*Q + b_f[rid]) -> LDS fp32 ----
        #pragma unroll
        for (int m2 = 0; m2 < 2; ++m2) {
            #pragma unroll
            for (int reg = 0; reg < 4; ++reg) {
                const int g = (wave * 2 + m2) * 16 + q * 4 + reg;
                #pragma unroll
                for (int bi = 0; bi < NBC; ++bi) {
                    int bl = ck * NBC + bi;
                    float p = 0.f;
                    #pragma unroll
                    for (int j = 0; j < 2; ++j) {
                        int nt = bi * 2 + j;
                        int n  = (j << 4) + t;
                        float Q   = acc[m2][nt][reg];
                        float d   = dall[bl][n];
                        float ccv = (float)chs[bi][n][g];
                        float bfv = bfl[rids[bl][n]][g];
                        p += ccv * d * fmaf(d, Q, bfv);
                    }
                    p += __shfl_xor(p, 1);
                    p += __shfl_xor(p, 2);
                    p += __shfl_xor(p, 4);
                    p += __shfl_xor(p, 8);
                    if (t == 0) csL[bl][g] = p;
                }
            }
        }
    }
    __syncthreads();

    // ================= gates: (16 x 512) @ (512 x 768), fused epilogue =================
    const int j0 = wave * 32;
    f32x4 accI[2], accO[2], accU[2];
    #pragma unroll
    for (int c = 0; c < 2; ++c)
        #pragma unroll
        for (int r = 0; r < 4; ++r) { accI[c][r] = 0.f; accO[c][r] = 0.f; accU[c][r] = 0.f; }

    #pragma unroll
    for (int kc = 0; kc < 16; ++kc) {
        const int k = kc * 32 + q * 8;
        bf16x8 a;
        if (kc < 8) a = ld8<F32>(ivec, (size_t)(b0 + t) * DIN_ + k);
        else        a = *(const bf16x8*)(&hsumL[t][k - 256]);
        #pragma unroll
        for (int c = 0; c < 2; ++c) {
            int j = j0 + c * 16 + t;
            bf16x8 bI = ld8<F32>(W_i, (size_t)j * 512 + k);
            bf16x8 bO = ld8<F32>(W_o, (size_t)j * 512 + k);
            bf16x8 bU = ld8<F32>(W_u, (size_t)j * 512 + k);
            accI[c] = __builtin_amdgcn_mfma_f32_16x16x32_bf16(a, bI, accI[c], 0, 0, 0);
            accO[c] = __builtin_amdgcn_mfma_f32_16x16x32_bf16(a, bO, accO[c], 0, 0, 0);
            accU[c] = __builtin_amdgcn_mfma_f32_16x16x32_bf16(a, bU, accU[c], 0, 0, 0);
        }
    }

    #pragma unroll
    for (int c = 0; c < 2; ++c) {
        const int j = j0 + c * 16 + t;
        float biv = ld1<F32>(b_i, j), bov = ld1<F32>(b_o, j), buv = ld1<F32>(b_u, j);
        #pragma unroll
        for (int reg = 0; reg < 4; ++reg) {
            int bl = q * 4 + reg;
            size_t o1 = (size_t)(b0 + bl) * H_ + j;
            size_t o2 = (size_t)B_ * H_ + o1;
            float iv = sigmoidf_(accI[c][reg] + biv);
            float ov = sigmoidf_(accO[c][reg] + bov);
            float uv = tanhf(accU[c][reg] + buv);
            float cv = fmaf(iv, uv, csL[bl][j]);
            float hv = ov * tanhf(cv);
            if constexpr (F32) {
                ((float*)outp)[o1] = hv;
                ((float*)outp)[o2] = cv;
            } else {
                ((bf16*)outp)[o1] = (bf16)hv;
                ((bf16*)outp)[o2] = (bf16)cv;
            }
        }
    }
}

extern "C" void kernel_launch(void* const* d_in, const int* in_sizes, int n_in,
                              void* d_out, int out_size, void* d_ws, size_t ws_size,
                              hipStream_t stream)
{
    const void* ivec    = d_in[0];
    const void* child_h = d_in[1];
    const void* child_c = d_in[2];
    const int*  relids  = (const int*)d_in[3];
    const void* vmask   = d_in[4];
    const void* rel_emb = d_in[5];
    const void* W_i     = d_in[6];
    const void* b_i     = d_in[7];
    const void* W_f     = d_in[8];
    const void* b_f     = d_in[9];
    const void* W_o     = d_in[10];
    const void* b_o     = d_in[11];
    const void* W_u     = d_in[12];
    const void* b_u     = d_in[13];
    const void* w_att   = d_in[14];
    const void* b_att   = d_in[15];

#define LAUNCH_VARIANT(F, M)                                                      \
    hipLaunchKernelGGL((fused_treelstm<F, M>), dim3(B_ / MB), dim3(512), 0,        \
                       stream, ivec, child_h, child_c, relids, vmask, rel_emb,     \
                       W_i, b_i, W_f, b_f, W_o, b_o, W_u, b_u, w_att, b_att, d_out)

    LAUNCH_VARIANT(false, false);
    LAUNCH_VARIANT(false, true);
    LAUNCH_VARIANT(true,  false);
    LAUNCH_VARIANT(true,  true);
#undef LAUNCH_VARIANT
}

// Round 4
// 485.271 us; speedup vs baseline: 1.5092x; 1.5092x over previous
//
#include <hip/hip_runtime.h>
#include <hip/hip_bf16.h>
#include <math.h>

// RelationAwareTreeLSTMCell on gfx950 — fp32 in/out (established round 3).
// B=4096 N=32 H=256 DIN=256 R=3.
// wprep: fp32 weights -> bf16 in d_ws (L2-resident working set, 1.15 MB).
// fused_main: 256 blocks x 512 thr, MB=16 batches/block, 8 chunks of NBC=2.
//   Per chunk: nt-stage child_h (fp32->bf16 LDS) -> attn dots/softmax/hsum ->
//   rid-masked MFMA GEMM Q=W_f[r]@ch -> nt-stage child_c -> fp32 cs epilogue.
//   Then gate GEMM (16 x 512)@(512 x 768) + fused sigmoid/tanh -> fp32 out.
// LDS 67.3 KB -> 2 blocks/CU (16 waves) so block barriers overlap across blocks.

#define B_    4096
#define N_    32
#define H_    256
#define DIN_  256
#define R_    3
#define MB    16
#define NBC   2
#define CHUNKS (MB / NBC)
#define DECAY 0.7f

// ws layout (bf16 elements)
#define WS_WF   0
#define WS_WI   196608
#define WS_WO   327680
#define WS_WU   458752
#define WS_ELEMS 589824                       // * 2 B = 1,179,648 B needed

typedef __bf16 bf16;
typedef bf16  bf16x8 __attribute__((ext_vector_type(8)));
typedef float f32x4  __attribute__((ext_vector_type(4)));

__device__ __forceinline__ float sigmoidf_(float x) { return 1.0f / (1.0f + __expf(-x)); }

// streamed fp32 -> bf16x8 (nontemporal: don't evict weights from L2)
__device__ __forceinline__ bf16x8 cvt8_nt(const float* p) {
    f32x4 a = __builtin_nontemporal_load((const f32x4*)p);
    f32x4 b = __builtin_nontemporal_load((const f32x4*)(p + 4));
    bf16x8 r;
    #pragma unroll
    for (int j = 0; j < 4; ++j) { r[j] = (bf16)a[j]; r[j + 4] = (bf16)b[j]; }
    return r;
}
// cached fp32 -> bf16x8 (weight fallback when ws too small)
__device__ __forceinline__ bf16x8 cvt8_c(const float* p) {
    f32x4 a = *(const f32x4*)p;
    f32x4 b = *(const f32x4*)(p + 4);
    bf16x8 r;
    #pragma unroll
    for (int j = 0; j < 4; ++j) { r[j] = (bf16)a[j]; r[j + 4] = (bf16)b[j]; }
    return r;
}

template<bool WSW>
__device__ __forceinline__ bf16x8 ldw8(const bf16* wsp, const float* fp, int idx) {
    if constexpr (WSW) return *(const bf16x8*)(wsp + idx);
    else               return cvt8_c(fp + idx);
}

// ---- weight prep: fp32 -> bf16 into d_ws. 288 blocks x 256 thr, exact cover. ----
__global__ __launch_bounds__(256) void wprep(
    const float* __restrict__ Wf, const float* __restrict__ Wi,
    const float* __restrict__ Wo, const float* __restrict__ Wu,
    bf16* __restrict__ ws)
{
    int i = (blockIdx.x * 256 + threadIdx.x) * 8;
    const float* src; int off;
    if      (i < WS_WI) { src = Wf; off = i - WS_WF; }
    else if (i < WS_WO) { src = Wi; off = i - WS_WI; }
    else if (i < WS_WU) { src = Wo; off = i - WS_WO; }
    else                { src = Wu; off = i - WS_WU; }
    *(bf16x8*)(ws + i) = cvt8_c(src + off);
}

template<bool WSW>
__global__ __launch_bounds__(512, 4) void fused_main(
    const float* __restrict__ ivec,
    const float* __restrict__ child_h, const float* __restrict__ child_c,
    const int*  __restrict__ rel_ids,  const void* __restrict__ vmaskp,
    const float* __restrict__ rel_emb,
    const float* __restrict__ W_i, const float* __restrict__ b_i,
    const float* __restrict__ W_f, const float* __restrict__ b_f,
    const float* __restrict__ W_o, const float* __restrict__ b_o,
    const float* __restrict__ W_u, const float* __restrict__ b_u,
    const float* __restrict__ w_att, const float* __restrict__ b_att,
    const bf16* __restrict__ ws, float* __restrict__ out)
{
    __shared__ __align__(16) bf16 chs[NBC][N_][264];   // 33792 B
    __shared__ __align__(16) bf16 hsumL[MB][264];      //  8448 B
    __shared__ float csL[MB][H_];                      // 16384 B
    __shared__ float watt[H_];                         //  1024 B
    __shared__ float bfl[R_][H_];                      //  3072 B
    __shared__ float dall[MB][N_];                     //  2048 B
    __shared__ int   rids[MB][N_];                     //  2048 B
    __shared__ float scoreT[NBC][N_];
    __shared__ float attnd[NBC][N_];
    __shared__ float rdotL[4];
    __shared__ int   m8flag;

    const int tid  = threadIdx.x;
    const int wave = tid >> 6;
    const int lane = tid & 63;
    const int t    = lane & 15;
    const int q    = lane >> 4;
    const int b0   = blockIdx.x * MB;

    const bf16* wfb = ws + WS_WF;
    const bf16* wib = ws + WS_WI;
    const bf16* wob = ws + WS_WO;
    const bf16* wub = ws + WS_WU;

    // ---- mask-format probe (wave 0): byte-bools have nonzero "upper bytes" ----
    if (tid < 64) {
        const unsigned char* vb = (const unsigned char*)vmaskp;
        int bad = vb[tid * 4 + 1] | vb[tid * 4 + 2] | vb[tid * 4 + 3];
        unsigned long long any = __ballot(bad != 0);
        if (tid == 0) m8flag = (any != 0ull) ? 1 : 0;
    }
    __syncthreads();

    // ---- small tables ----
    if (tid < H_) watt[tid] = w_att[tid];
    {
        int idx = b0 * N_ + tid;           // MB*N_ == 512 == blockDim
        rids[tid >> 5][tid & 31] = rel_ids[idx];
        bool vm = m8flag ? (((const unsigned char*)vmaskp)[idx] != 0)
                         : (((const int*)vmaskp)[idx] != 0);
        dall[tid >> 5][tid & 31] = vm ? DECAY : 1.0f;
    }
    if (tid >= 512 - R_ * 64 && false) {}  // (no-op; keep wave mapping simple)
    for (int i = tid; i < R_ * H_; i += 512) ((float*)bfl)[i] = b_f[i];
    if (tid == 0) rdotL[3] = b_att[0];
    __syncthreads();

    // rdot[r] = dot(rel_emb[r], w_att); published by the chunk-loop-top barrier
    if (wave < R_) {
        int r = wave;
        float p = 0.f;
        #pragma unroll
        for (int j = 0; j < 4; ++j) {
            int h = lane * 4 + j;
            p += rel_emb[r * H_ + h] * watt[h];
        }
        #pragma unroll
        for (int off = 32; off >= 1; off >>= 1) p += __shfl_xor(p, off);
        if (lane == 0) rdotL[r] = p;
    }

    // ================= chunk loop: NBC=2 batches each =================
    for (int ck = 0; ck < CHUNKS; ++ck) {
        __syncthreads();

        // ---- stage child_h chunk (nt fp32 -> bf16 LDS) ----
        {
            size_t base = (size_t)(b0 + ck * NBC) * (N_ * H_);
            #pragma unroll
            for (int it = 0; it < 4; ++it) {
                int ge = (it * 512 + tid) << 3;              // 0..16376
                int bi = ge >> 13, n = (ge >> 8) & 31, h = ge & 255;
                *(bf16x8*)(&chs[bi][n][h]) = cvt8_nt(child_h + base + ge);
            }
        }
        __syncthreads();

        // ---- attention dots t_n = <ch_n, w_att> (8 lanes / (bi,n) pair) ----
        {
            int pair = tid >> 3, part = tid & 7;
            int bi = pair >> 5, n = pair & 31;
            const bf16* row = chs[bi][n];
            float p = 0.f;
            #pragma unroll
            for (int jj = 0; jj < 4; ++jj) {
                bf16x8 v = *(const bf16x8*)(&row[part * 32 + jj * 8]);
                #pragma unroll
                for (int j = 0; j < 8; ++j) p += (float)v[j] * watt[part * 32 + jj * 8 + j];
            }
            p += __shfl_xor(p, 1);
            p += __shfl_xor(p, 2);
            p += __shfl_xor(p, 4);
            if (part == 0) scoreT[bi][n] = p;
        }
        __syncthreads();

        // ---- softmax over n ----
        if (tid < NBC * N_) {
            int bi = tid >> 5, n = tid & 31;
            int bl = ck * NBC + bi;
            float d = dall[bl][n];
            float s = d * scoreT[bi][n] + rdotL[rids[bl][n]] + rdotL[3];
            float m = s;
            #pragma unroll
            for (int off = 16; off >= 1; off >>= 1) m = fmaxf(m, __shfl_xor(m, off));
            float e = __expf(s - m);
            float sum = e;
            #pragma unroll
            for (int off = 16; off >= 1; off >>= 1) sum += __shfl_xor(sum, off);
            attnd[bi][n] = (e / sum) * d;   // attn * decay
        }
        __syncthreads();

        // ---- h_sum -> LDS (bf16) ----
        {
            int bi = tid >> 8, g = tid & 255;
            int bl = ck * NBC + bi;
            float s = 0.f;
            #pragma unroll 8
            for (int n = 0; n < N_; ++n) s += attnd[bi][n] * (float)chs[bi][n][g];
            hsumL[bl][g] = (bf16)s;
        }

        // ---- rid-masked MFMA GEMM: Q[g,n] (M=256, N=32, K=3x256) ----
        f32x4 acc[2][4];
        #pragma unroll
        for (int i = 0; i < 2; ++i)
            #pragma unroll
            for (int j = 0; j < 4; ++j)
                #pragma unroll
                for (int c = 0; c < 4; ++c) acc[i][j][c] = 0.0f;

        bf16x8 bzero;
        #pragma unroll
        for (int i = 0; i < 8; ++i) bzero[i] = (bf16)0.0f;

        int myrid[4];
        #pragma unroll
        for (int nt = 0; nt < 4; ++nt)
            myrid[nt] = rids[ck * NBC + (nt >> 1)][((nt & 1) << 4) + t];

        #pragma unroll
        for (int kc = 0; kc < 8; ++kc) {
            const int k = kc * 32 + q * 8;
            bf16x8 v[4];
            #pragma unroll
            for (int nt = 0; nt < 4; ++nt)
                v[nt] = *(const bf16x8*)(&chs[nt >> 1][((nt & 1) << 4) + t][k]);
            #pragma unroll
            for (int r = 0; r < R_; ++r) {
                bf16x8 afrag[2];
                #pragma unroll
                for (int m2 = 0; m2 < 2; ++m2) {
                    int g = (wave * 2 + m2) * 16 + t;
                    afrag[m2] = ldw8<WSW>(wfb, W_f, (r * H_ + g) * H_ + k);
                }
                #pragma unroll
                for (int nt = 0; nt < 4; ++nt) {
                    bf16x8 vm = (myrid[nt] == r) ? v[nt] : bzero;
                    acc[0][nt] = __builtin_amdgcn_mfma_f32_16x16x32_bf16(afrag[0], vm, acc[0][nt], 0, 0, 0);
                    acc[1][nt] = __builtin_amdgcn_mfma_f32_16x16x32_bf16(afrag[1], vm, acc[1][nt], 0, 0, 0);
                }
            }
        }
        __syncthreads();

        // ---- stage child_c chunk (overwrite chs) ----
        {
            size_t base = (size_t)(b0 + ck * NBC) * (N_ * H_);
            #pragma unroll
            for (int it = 0; it < 4; ++it) {
                int ge = (it * 512 + tid) << 3;
                int bi = ge >> 13, n = (ge >> 8) & 31, h = ge & 255;
                *(bf16x8*)(&chs[bi][n][h]) = cvt8_nt(child_c + base + ge);
            }
        }
        __syncthreads();

        // ---- cs[bl][g] = sum_n cc*d*(d*Q + b_f[rid]) -> LDS fp32 ----
        #pragma unroll
        for (int m2 = 0; m2 < 2; ++m2) {
            #pragma unroll
            for (int reg = 0; reg < 4; ++reg) {
                const int g = (wave * 2 + m2) * 16 + q * 4 + reg;
                #pragma unroll
                for (int bi = 0; bi < NBC; ++bi) {
                    int bl = ck * NBC + bi;
                    float p = 0.f;
                    #pragma unroll
                    for (int j = 0; j < 2; ++j) {
                        int nt = bi * 2 + j;
                        int n  = (j << 4) + t;
                        float Q   = acc[m2][nt][reg];
                        float d   = dall[bl][n];
                        float ccv = (float)chs[bi][n][g];
                        float bfv = bfl[rids[bl][n]][g];
                        p += ccv * d * fmaf(d, Q, bfv);
                    }
                    p += __shfl_xor(p, 1);
                    p += __shfl_xor(p, 2);
                    p += __shfl_xor(p, 4);
                    p += __shfl_xor(p, 8);
                    if (t == 0) csL[bl][g] = p;
                }
            }
        }
    }
    __syncthreads();

    // ================= gates: (16 x 512) @ (512 x 768), fused epilogue =================
    const int j0 = wave * 32;
    f32x4 accI[2], accO[2], accU[2];
    #pragma unroll
    for (int c = 0; c < 2; ++c)
        #pragma unroll
        for (int r = 0; r < 4; ++r) { accI[c][r] = 0.f; accO[c][r] = 0.f; accU[c][r] = 0.f; }

    #pragma unroll
    for (int kc = 0; kc < 16; ++kc) {
        const int k = kc * 32 + q * 8;
        bf16x8 a;
        if (kc < 8) a = cvt8_nt(ivec + (size_t)(b0 + t) * DIN_ + k);
        else        a = *(const bf16x8*)(&hsumL[t][k - 256]);
        #pragma unroll
        for (int c = 0; c < 2; ++c) {
            int j = j0 + c * 16 + t;
            bf16x8 bI = ldw8<WSW>(wib, W_i, j * 512 + k);
            bf16x8 bO = ldw8<WSW>(wob, W_o, j * 512 + k);
            bf16x8 bU = ldw8<WSW>(wub, W_u, j * 512 + k);
            accI[c] = __builtin_amdgcn_mfma_f32_16x16x32_bf16(a, bI, accI[c], 0, 0, 0);
            accO[c] = __builtin_amdgcn_mfma_f32_16x16x32_bf16(a, bO, accO[c], 0, 0, 0);
            accU[c] = __builtin_amdgcn_mfma_f32_16x16x32_bf16(a, bU, accU[c], 0, 0, 0);
        }
    }

    #pragma unroll
    for (int c = 0; c < 2; ++c) {
        const int j = j0 + c * 16 + t;
        float biv = b_i[j], bov = b_o[j], buv = b_u[j];
        #pragma unroll
        for (int reg = 0; reg < 4; ++reg) {
            int bl = q * 4 + reg;
            size_t o1 = (size_t)(b0 + bl) * H_ + j;
            size_t o2 = (size_t)B_ * H_ + o1;
            float iv = sigmoidf_(accI[c][reg] + biv);
            float ov = sigmoidf_(accO[c][reg] + bov);
            float uv = tanhf(accU[c][reg] + buv);
            float cv = fmaf(iv, uv, csL[bl][j]);
            float hv = ov * tanhf(cv);
            __builtin_nontemporal_store(hv, out + o1);
            __builtin_nontemporal_store(cv, out + o2);
        }
    }
}

extern "C" void kernel_launch(void* const* d_in, const int* in_sizes, int n_in,
                              void* d_out, int out_size, void* d_ws, size_t ws_size,
                              hipStream_t stream)
{
    const float* ivec    = (const float*)d_in[0];
    const float* child_h = (const float*)d_in[1];
    const float* child_c = (const float*)d_in[2];
    const int*   relids  = (const int*)d_in[3];
    const void*  vmask   = d_in[4];
    const float* rel_emb = (const float*)d_in[5];
    const float* W_i     = (const float*)d_in[6];
    const float* b_i     = (const float*)d_in[7];
    const float* W_f     = (const float*)d_in[8];
    const float* b_f     = (const float*)d_in[9];
    const float* W_o     = (const float*)d_in[10];
    const float* b_o     = (const float*)d_in[11];
    const float* W_u     = (const float*)d_in[12];
    const float* b_u     = (const float*)d_in[13];
    const float* w_att   = (const float*)d_in[14];
    const float* b_att   = (const float*)d_in[15];
    float* out = (float*)d_out;
    bf16*  ws  = (bf16*)d_ws;

    const bool wsw = (ws_size >= (size_t)WS_ELEMS * sizeof(bf16));

    if (wsw) {
        hipLaunchKernelGGL(wprep, dim3(WS_ELEMS / 8 / 256), dim3(256), 0, stream,
                           W_f, W_i, W_o, W_u, ws);
        hipLaunchKernelGGL((fused_main<true>), dim3(B_ / MB), dim3(512), 0, stream,
                           ivec, child_h, child_c, relids, vmask, rel_emb,
                           W_i, b_i, W_f, b_f, W_o, b_o, W_u, b_u, w_att, b_att,
                           ws, out);
    } else {
        hipLaunchKernelGGL((fused_main<false>), dim3(B_ / MB), dim3(512), 0, stream,
                           ivec, child_h, child_c, relids, vmask, rel_emb,
                           W_i, b_i, W_f, b_f, W_o, b_o, W_u, b_u, w_att, b_att,
                           ws, out);
    }
}